// Round 5
// baseline (76.387 us; speedup 1.0000x reference)
//
#include <hip/hip_runtime.h>

#define BB 64
#define TT 12
#define NL 2000
#define PP 20
#define CLS 2
#define BIGF 1.0e9f

#define TPB   256                 // 4 waves per block -> no forced multi-wave
                                  // VGPR cap (512-thr blocks hard-capped at 128
                                  // twice: r3/r4 -> 15MB scratch spill)
#define NWAVE 4
#define LPB   250                 // lines per block
#define NBLK  8                   // NL / LPB
#define NSLOT NBLK
#define NBLOCKS (NBLK * BB)       // 512 blocks = 2/CU

// ws layout (uint32 units), [t][s][b] so final reads coalesce over b:
//   mind2 : [(t*NSLOT + s)*BB + b]      (floats)
//   cmask : [OFF_CM  + s*BB + b]
//   cnt   : [OFF_CNT + s*BB + b]
//   ctr   : [OFF_CTR]  ticket counter, zeroed by a 4-byte memset node
#define OFF_CM  (TT * NSLOT * BB)
#define OFF_CNT (TT * NSLOT * BB + NSLOT * BB)
#define OFF_CTR (TT * NSLOT * BB + 2 * NSLOT * BB)
// total 7169 u32 ~= 28.7 KB of d_ws

// (256,1): min-waves=1 is the least restrictive allocator request. Observed
// caps: (256,4)->64, (64,2)->128, (512,none)->128 — all spilled ~30-50
// dwords/thread to scratch (13-68 MB HBM write-back, serialized inner loops).
__global__ __launch_bounds__(TPB, 1) void gtmb_fused(
    const float* __restrict__ pred,    // B,T,2
    const float* __restrict__ pts,     // B,N,1,P,2
    const int*   __restrict__ labels,  // B,N
    const float* __restrict__ masks,   // B,T
    unsigned int* __restrict__ ws,
    float* __restrict__ out) {
    const int b    = blockIdx.y;
    const int blk  = blockIdx.x;       // chunk of 250 lines
    const int tid  = threadIdx.x;
    const int lane = tid & 63, wave = tid >> 6;

    __shared__ unsigned short sidx[LPB];
    __shared__ int wcnt[NWAVE];
    __shared__ float sred[NWAVE][TT];
    __shared__ unsigned int scmw[NWAVE];
    __shared__ int slast;
    __shared__ float smf[TT * BB];              // final-stage only
    __shared__ unsigned int scm[BB], shas[BB];  // final-stage only

    // ---- phase 1: ballot compaction of valid lines (4-wave LDS prefix) ----
    const int base = blk * LPB;        // 250*blk: always even -> int2-aligned
    int v0 = 0, v1 = 0, n0 = 0;
    if (tid < LPB / 2) {               // 125 int2 = 250 labels
        n0 = base + 2 * tid;
        int2 lb = *reinterpret_cast<const int2*>(labels + b * NL + n0);
        v0 = (lb.x == CLS);
        v1 = (lb.y == CLS);
    }
    unsigned long long m0 = __ballot(v0);
    unsigned long long m1 = __ballot(v1);
    unsigned long long lt = (1ull << lane) - 1ull;
    if (lane == 0) wcnt[wave] = __popcll(m0) + __popcll(m1);
    __syncthreads();
    int off = 0, cnt = 0;
#pragma unroll
    for (int w2 = 0; w2 < NWAVE; ++w2) {
        int c = wcnt[w2];
        if (w2 < wave) off += c;
        cnt += c;
    }
    const int c0 = __popcll(m0);
    if (v0) sidx[off + __popcll(m0 & lt)]      = (unsigned short)n0;
    if (v1) sidx[off + c0 + __popcll(m1 & lt)] = (unsigned short)(n0 + 1);
    __syncthreads();

    // ---- trajectory (block-uniform, compiler scalarizes) ----
    float ex[TT], ey[TT];
    const float* pb = pred + b * (TT * 2);
#pragma unroll
    for (int t = 0; t < TT; ++t) { ex[t] = pb[2*t]; ey[t] = pb[2*t+1]; }

    float mind2[TT];
#pragma unroll
    for (int t = 0; t < TT; ++t) mind2[t] = BIGF;
    unsigned int cmask = 0;

    // ---- phase 2: dense items, one half-line (10 pts / 10 segs) per item ----
    // nitems = 2*cnt ~ 125+-14 << 256 -> single pass, no 2-round tail.
    const int nitems = 2 * cnt;
    for (int w = tid; w < nitems; w += TPB) {
        const int ln = sidx[w >> 1];
        const int h  = w & 1;
        const float4* lp = reinterpret_cast<const float4*>(
                               pts + (long)(b * NL + ln) * (PP * 2)) + h * 5;
        float4 q0 = lp[0], q1 = lp[1], q2 = lp[2], q3 = lp[3], q4 = lp[4];
        float p10x = q4.z, p10y = q4.w;          // h=1: dup of p9 (degenerate)
        if (h == 0) { float4 q5 = lp[5]; p10x = q5.x; p10y = q5.y; }

        float px[11], py[11];
        px[0]=q0.x; py[0]=q0.y;  px[1]=q0.z; py[1]=q0.w;
        px[2]=q1.x; py[2]=q1.y;  px[3]=q1.z; py[3]=q1.w;
        px[4]=q2.x; py[4]=q2.y;  px[5]=q2.z; py[5]=q2.w;
        px[6]=q3.x; py[6]=q3.y;  px[7]=q3.z; py[7]=q3.w;
        px[8]=q4.x; py[8]=q4.y;  px[9]=q4.z; py[9]=q4.w;
        px[10]=p10x; py[10]=p10y;

        // min distance^2: pts 0..9 (pt 10 is the next half's pt 0)
#pragma unroll
        for (int i = 0; i < 10; ++i) {
#pragma unroll
            for (int t = 0; t < TT; ++t) {
                float dx = px[i] - ex[t];
                float dy = py[i] - ey[t];
                mind2[t] = fminf(mind2[t], fmaf(dx, dx, dy * dy));
            }
        }

        // segment intersection: segs (i,i+1), i=0..9
#pragma unroll
        for (int i = 0; i < 10; ++i) {
            float dx2 = px[i+1] - px[i];
            float dy2 = py[i+1] - py[i];
#pragma unroll
            for (int t = 0; t < TT; ++t) {
                float sx = t ? ex[t-1] : 0.0f;
                float sy = t ? ey[t-1] : 0.0f;
                float dxt = ex[t] - sx;
                float dyt = ey[t] - sy;
                float rx = px[i] - sx;
                float ry = py[i] - sy;
                float det = dxt * dy2 - dx2 * dyt;
                float n1  = rx * dy2 - ry * dx2;
                float n2  = rx * dyt - ry * dxt;
                // sign-xor form: boolean-identical to
                //   det>0 ? (0<=n1<=det && 0<=n2<=det)
                //         : det<0 ? (det<=n1<=0 && det<=n2<=0) : false
                unsigned int sb = __float_as_uint(det) & 0x80000000u;
                float n1x = __uint_as_float(__float_as_uint(n1) ^ sb);
                float n2x = __uint_as_float(__float_as_uint(n2) ^ sb);
                float ad  = fabsf(det);
                bool hit = (n1x >= 0.0f) & (n1x <= ad) &
                           (n2x >= 0.0f) & (n2x <= ad) & (det != 0.0f);
                if (hit) cmask |= (1u << t);
            }
        }
    }

    // ---- wave64 reduce, cross-wave via LDS, one slot write per block ----
#pragma unroll
    for (int t = 0; t < TT; ++t) {
        float v = mind2[t];
        for (int o = 32; o; o >>= 1) v = fminf(v, __shfl_xor(v, o));
        mind2[t] = v;
    }
    for (int o = 32; o; o >>= 1) cmask |= __shfl_xor(cmask, o);

    if (lane == 0) {
#pragma unroll
        for (int t = 0; t < TT; ++t) sred[wave][t] = mind2[t];
        scmw[wave] = cmask;
    }
    __syncthreads();
    float* wfw = (float*)ws;
    if (tid < TT) {
        float v = sred[0][tid];
#pragma unroll
        for (int w2 = 1; w2 < NWAVE; ++w2) v = fminf(v, sred[w2][tid]);
        wfw[(tid * NSLOT + blk) * BB + b] = v;
    } else if (tid == 16) {
        unsigned int cm = scmw[0] | scmw[1] | scmw[2] | scmw[3];
        ws[OFF_CM + blk * BB + b] = cm;
    } else if (tid == 17) {
        ws[OFF_CNT + blk * BB + b] = (unsigned int)cnt;
    }

    // ---- ticket: release partials, last block runs the final stage ----
    // canonical threadFenceReduction pattern; device-scope fence + atomic
    // handles cross-XCD L2 visibility (G12/G16).
    __threadfence();                       // release (each storer flushes)
    __syncthreads();
    if (tid == 0) {
        unsigned int old = atomicAdd(&ws[OFF_CTR], 1u);
        slast = (old == (unsigned int)(NBLOCKS - 1));
    }
    __syncthreads();
    if (!slast) return;                    // block-uniform: no divergent syncs
    // keep ALL epilogue code/address-math below this point so it cannot be
    // hoisted into the main loop and inflate its register pressure (the r3
    // fusion spilled exactly this way: VGPR capped 128, 15 MB scratch).
    __builtin_amdgcn_sched_barrier(0);
    __threadfence();                       // acquire (invalidate stale caches)

    // ---- final stage (last block only, 256 threads = 4 waves) ----
    const float* wf = (const float*)ws;
    const int fb = tid & 63, g = tid >> 6;  // g = 0..3
#pragma unroll
    for (int k = 0; k < 3; ++k) {           // wave g handles t = 3g..3g+2
        const int t = 3 * g + k;
        float m = BIGF;
#pragma unroll
        for (int s = 0; s < NSLOT; ++s)
            m = fminf(m, wf[(t * NSLOT + s) * BB + fb]);
        smf[t * BB + fb] = m;
    }
    if (g == 0) {
        unsigned int cm = 0;
#pragma unroll
        for (int s = 0; s < NSLOT; ++s) cm |= ws[OFF_CM + s * BB + fb];
        scm[fb] = cm;
    } else if (g == 1) {
        unsigned int has = 0;
#pragma unroll
        for (int s = 0; s < NSLOT; ++s) has |= ws[OFF_CNT + s * BB + fb];
        shas[fb] = has;
    }
    __syncthreads();

    if (tid < BB) {  // wave 0: thread = batch
        const bool hl = shas[fb] != 0;
        const unsigned int cm = scm[fb];
        const float4 mk0 = *reinterpret_cast<const float4*>(masks + fb * TT);
        const float4 mk1 = *reinterpret_cast<const float4*>(masks + fb * TT + 4);
        const float4 mk2 = *reinterpret_cast<const float4*>(masks + fb * TT + 8);
        const float mk[TT] = {mk0.x, mk0.y, mk0.z, mk0.w,
                              mk1.x, mk1.y, mk1.z, mk1.w,
                              mk2.x, mk2.y, mk2.z, mk2.w};
        float total = 0.0f, csum = 0.0f;
        bool blocked = false;
#pragma unroll
        for (int t = 0; t < TT; ++t) {
            bool valid_t = (mk[t] >= 0.5f) && hl;
            bool trig = valid_t && ((cm >> t) & 1u);
            blocked = blocked || trig;
            if (valid_t && !blocked) {
                float d = sqrtf(smf[t * BB + fb]);
                total += fmaxf(1.0f - d, 0.0f);
                csum += 1.0f;
            }
        }
        for (int o = 32; o; o >>= 1) {
            total += __shfl_xor(total, o);
            csum  += __shfl_xor(csum, o);
        }
        if (fb == 0) out[0] = (csum == 0.0f) ? 0.0f : total / fmaxf(csum, 1.0f);
    }
}

extern "C" void kernel_launch(void* const* d_in, const int* in_sizes, int n_in,
                              void* d_out, int out_size, void* d_ws, size_t ws_size,
                              hipStream_t stream) {
    const float* pred   = (const float*)d_in[0];
    const float* pts    = (const float*)d_in[1];
    const int*   labels = (const int*)d_in[2];
    const float* masks  = (const float*)d_in[3];
    float* out = (float*)d_out;
    unsigned int* ws = (unsigned int*)d_ws;

    // zero the ticket counter (ws is poisoned between iterations);
    // 4-byte memset node, graph-capturable, DMA path.
    hipMemsetAsync((char*)d_ws + OFF_CTR * sizeof(unsigned int), 0,
                   sizeof(unsigned int), stream);

    dim3 grid(NBLK, BB);
    gtmb_fused<<<grid, TPB, 0, stream>>>(pred, pts, labels, masks, ws, out);
}

// Round 6
// 38.041 us; speedup vs baseline: 2.0080x; 2.0080x over previous
//
#include <hip/hip_runtime.h>

#define BB 64
#define TT 12
#define NL 2000
#define PP 20
#define CLS 2
#define BIGF 1.0e9f

#define TPB   256                 // 4 waves; (256,1) proven: VGPR 160, no spill
#define NWAVE 4
#define LPB   250                 // lines per block
#define NBLK  8                   // NL / LPB
#define NBLOCKS (NBLK * BB)       // 512 blocks

// ws layout (uint32 units) — ALL slots combined via device-scope atomics
// (fence-free: atomics act at the device coherence point; __threadfence's
// buffer_wbl2 L2-flush cost ~65us across 512 blocks in r4 -> removed).
//   mdneg : [t*BB + b]   atomicMax of ~bits(mind2)  (uint-max of complemented
//                        bits == float-min; init 0 loses to any real value)
//   cm    : [OFF_CM + b]  atomicOr of cmask
//   has   : [OFF_HAS + b] atomicOr of cnt
//   ctr   : [OFF_CTR]     ticket
#define OFF_CM  (TT * BB)
#define OFF_HAS (TT * BB + BB)
#define OFF_CTR (TT * BB + 2 * BB)
#define WS_U32  (TT * BB + 2 * BB + 1)   // 897 u32 = 3588 B, one memset-0 node

__global__ __launch_bounds__(TPB, 1) void gtmb_fused(
    const float* __restrict__ pred,    // B,T,2
    const float* __restrict__ pts,     // B,N,1,P,2
    const int*   __restrict__ labels,  // B,N
    const float* __restrict__ masks,   // B,T
    unsigned int* __restrict__ ws,
    float* __restrict__ out) {
    const int b    = blockIdx.y;
    const int blk  = blockIdx.x;       // chunk of 250 lines
    const int tid  = threadIdx.x;
    const int lane = tid & 63, wave = tid >> 6;

    __shared__ unsigned short sidx[LPB];
    __shared__ int wcnt[NWAVE];
    __shared__ float sred[NWAVE][TT];
    __shared__ unsigned int scmw[NWAVE];
    __shared__ int slast;
    __shared__ float smf[TT * BB];              // final-stage only
    __shared__ unsigned int scm[BB], shas[BB];  // final-stage only

    // ---- phase 1: ballot compaction of valid lines (4-wave LDS prefix) ----
    const int base = blk * LPB;        // 250*blk: always even -> int2-aligned
    int v0 = 0, v1 = 0, n0 = 0;
    if (tid < LPB / 2) {               // 125 int2 = 250 labels
        n0 = base + 2 * tid;
        int2 lb = *reinterpret_cast<const int2*>(labels + b * NL + n0);
        v0 = (lb.x == CLS);
        v1 = (lb.y == CLS);
    }
    unsigned long long m0 = __ballot(v0);
    unsigned long long m1 = __ballot(v1);
    unsigned long long lt = (1ull << lane) - 1ull;
    if (lane == 0) wcnt[wave] = __popcll(m0) + __popcll(m1);
    __syncthreads();
    int off = 0, cnt = 0;
#pragma unroll
    for (int w2 = 0; w2 < NWAVE; ++w2) {
        int c = wcnt[w2];
        if (w2 < wave) off += c;
        cnt += c;
    }
    const int c0 = __popcll(m0);
    if (v0) sidx[off + __popcll(m0 & lt)]      = (unsigned short)n0;
    if (v1) sidx[off + c0 + __popcll(m1 & lt)] = (unsigned short)(n0 + 1);
    __syncthreads();

    // ---- trajectory (block-uniform, compiler scalarizes) ----
    float ex[TT], ey[TT];
    const float* pb = pred + b * (TT * 2);
#pragma unroll
    for (int t = 0; t < TT; ++t) { ex[t] = pb[2*t]; ey[t] = pb[2*t+1]; }

    float mind2[TT];
#pragma unroll
    for (int t = 0; t < TT; ++t) mind2[t] = BIGF;
    unsigned int cmask = 0;

    // ---- phase 2: dense items, one half-line (10 pts / 10 segs) per item ----
    // nitems = 2*cnt ~ 125+-14 << 256 -> single pass, no 2-round tail.
    const int nitems = 2 * cnt;
    for (int w = tid; w < nitems; w += TPB) {
        const int ln = sidx[w >> 1];
        const int h  = w & 1;
        const float4* lp = reinterpret_cast<const float4*>(
                               pts + (long)(b * NL + ln) * (PP * 2)) + h * 5;
        float4 q0 = lp[0], q1 = lp[1], q2 = lp[2], q3 = lp[3], q4 = lp[4];
        float p10x = q4.z, p10y = q4.w;          // h=1: dup of p9 (degenerate)
        if (h == 0) { float4 q5 = lp[5]; p10x = q5.x; p10y = q5.y; }

        float px[11], py[11];
        px[0]=q0.x; py[0]=q0.y;  px[1]=q0.z; py[1]=q0.w;
        px[2]=q1.x; py[2]=q1.y;  px[3]=q1.z; py[3]=q1.w;
        px[4]=q2.x; py[4]=q2.y;  px[5]=q2.z; py[5]=q2.w;
        px[6]=q3.x; py[6]=q3.y;  px[7]=q3.z; py[7]=q3.w;
        px[8]=q4.x; py[8]=q4.y;  px[9]=q4.z; py[9]=q4.w;
        px[10]=p10x; py[10]=p10y;

        // min distance^2: pts 0..9 (pt 10 is the next half's pt 0)
#pragma unroll
        for (int i = 0; i < 10; ++i) {
#pragma unroll
            for (int t = 0; t < TT; ++t) {
                float dx = px[i] - ex[t];
                float dy = py[i] - ey[t];
                mind2[t] = fminf(mind2[t], fmaf(dx, dx, dy * dy));
            }
        }

        // segment intersection: segs (i,i+1), i=0..9
#pragma unroll
        for (int i = 0; i < 10; ++i) {
            float dx2 = px[i+1] - px[i];
            float dy2 = py[i+1] - py[i];
#pragma unroll
            for (int t = 0; t < TT; ++t) {
                float sx = t ? ex[t-1] : 0.0f;
                float sy = t ? ey[t-1] : 0.0f;
                float dxt = ex[t] - sx;
                float dyt = ey[t] - sy;
                float rx = px[i] - sx;
                float ry = py[i] - sy;
                float det = dxt * dy2 - dx2 * dyt;
                float n1  = rx * dy2 - ry * dx2;
                float n2  = rx * dyt - ry * dxt;
                // sign-xor form: boolean-identical to
                //   det>0 ? (0<=n1<=det && 0<=n2<=det)
                //         : det<0 ? (det<=n1<=0 && det<=n2<=0) : false
                unsigned int sb = __float_as_uint(det) & 0x80000000u;
                float n1x = __uint_as_float(__float_as_uint(n1) ^ sb);
                float n2x = __uint_as_float(__float_as_uint(n2) ^ sb);
                float ad  = fabsf(det);
                bool hit = (n1x >= 0.0f) & (n1x <= ad) &
                           (n2x >= 0.0f) & (n2x <= ad) & (det != 0.0f);
                if (hit) cmask |= (1u << t);
            }
        }
    }

    // ---- wave64 reduce, cross-wave via LDS ----
#pragma unroll
    for (int t = 0; t < TT; ++t) {
        float v = mind2[t];
        for (int o = 32; o; o >>= 1) v = fminf(v, __shfl_xor(v, o));
        mind2[t] = v;
    }
    for (int o = 32; o; o >>= 1) cmask |= __shfl_xor(cmask, o);

    if (lane == 0) {
#pragma unroll
        for (int t = 0; t < TT; ++t) sred[wave][t] = mind2[t];
        scmw[wave] = cmask;
    }
    __syncthreads();

    // ---- publish partials via device atomics (fence-free, exact, order-free)
    // all publishers in wave 0, same wave as the ticket thread.
    if (tid < TT) {
        float v = sred[0][tid];
#pragma unroll
        for (int w2 = 1; w2 < NWAVE; ++w2) v = fminf(v, sred[w2][tid]);
        atomicMax(&ws[tid * BB + b], ~__float_as_uint(v));
    } else if (tid == 16) {
        unsigned int cm = scmw[0] | scmw[1] | scmw[2] | scmw[3];
        atomicOr(&ws[OFF_CM + b], cm);
    } else if (tid == 17) {
        atomicOr(&ws[OFF_HAS + b], (unsigned int)cnt);
    }
    // wave-local drain: our 14 atomics reach the coherence point before the
    // ticket increment is issued. NOT an L2 flush (that was r4's 65us).
    asm volatile("s_waitcnt vmcnt(0)" ::: "memory");
    __syncthreads();
    if (tid == 0) {
        unsigned int old = atomicAdd(&ws[OFF_CTR], 1u);
        slast = (old == (unsigned int)(NBLOCKS - 1));
    }
    __syncthreads();
    if (!slast) return;                    // block-uniform exit
    __builtin_amdgcn_sched_barrier(0);     // keep epilogue below the loop

    // ---- final stage (last block only, 256 threads = 4 waves) ----
    // reads via no-op RMWs: return value comes from the coherence point.
    const int fb = tid & 63, g = tid >> 6;  // g = 0..3
#pragma unroll
    for (int k = 0; k < 3; ++k) {           // wave g handles t = 3g..3g+2
        const int t = 3 * g + k;
        unsigned int raw = atomicMax(&ws[t * BB + fb], 0u);  // no-op, ret old
        smf[t * BB + fb] = __uint_as_float(~raw);
    }
    if (g == 0) {
        scm[fb] = atomicOr(&ws[OFF_CM + fb], 0u);
    } else if (g == 1) {
        shas[fb] = atomicOr(&ws[OFF_HAS + fb], 0u);
    }
    __syncthreads();

    if (tid < BB) {  // wave 0: thread = batch
        const bool hl = shas[fb] != 0;
        const unsigned int cm = scm[fb];
        const float4 mk0 = *reinterpret_cast<const float4*>(masks + fb * TT);
        const float4 mk1 = *reinterpret_cast<const float4*>(masks + fb * TT + 4);
        const float4 mk2 = *reinterpret_cast<const float4*>(masks + fb * TT + 8);
        const float mk[TT] = {mk0.x, mk0.y, mk0.z, mk0.w,
                              mk1.x, mk1.y, mk1.z, mk1.w,
                              mk2.x, mk2.y, mk2.z, mk2.w};
        float total = 0.0f, csum = 0.0f;
        bool blocked = false;
#pragma unroll
        for (int t = 0; t < TT; ++t) {
            bool valid_t = (mk[t] >= 0.5f) && hl;
            bool trig = valid_t && ((cm >> t) & 1u);
            blocked = blocked || trig;
            if (valid_t && !blocked) {
                float d = sqrtf(smf[t * BB + fb]);
                total += fmaxf(1.0f - d, 0.0f);
                csum += 1.0f;
            }
        }
        for (int o = 32; o; o >>= 1) {
            total += __shfl_xor(total, o);
            csum  += __shfl_xor(csum, o);
        }
        if (fb == 0) out[0] = (csum == 0.0f) ? 0.0f : total / fmaxf(csum, 1.0f);
    }
}

extern "C" void kernel_launch(void* const* d_in, const int* in_sizes, int n_in,
                              void* d_out, int out_size, void* d_ws, size_t ws_size,
                              hipStream_t stream) {
    const float* pred   = (const float*)d_in[0];
    const float* pts    = (const float*)d_in[1];
    const int*   labels = (const int*)d_in[2];
    const float* masks  = (const float*)d_in[3];
    float* out = (float*)d_out;
    unsigned int* ws = (unsigned int*)d_ws;

    // one memset-0 node inits everything: mdneg slots (0 loses to any
    // published ~bits value), cm/has (OR identity), ticket. 3.6 KB, DMA path.
    hipMemsetAsync(d_ws, 0, WS_U32 * sizeof(unsigned int), stream);

    dim3 grid(NBLK, BB);
    gtmb_fused<<<grid, TPB, 0, stream>>>(pred, pts, labels, masks, ws, out);
}